// Round 5
// baseline (722.925 us; speedup 1.0000x reference)
//
#include <hip/hip_runtime.h>

// Problem constants (fixed by reference setup_inputs).
#define N 32
#define T 64
#define C 256
#define L 64

// Workspace layout:
//   [0, 512 KiB)            partial[t][n][l]   (T*N*L floats)
//   [512K, 512K+128)        done[n]   (N u32)  -- zeroed by hipMemsetAsync
//   [512K+128, 512K+256)    flag[n]   (N u32)  -- zeroed by hipMemsetAsync
//   [512K+256, +8 KiB)      probs_g[n][l]      (N*L floats)
//
// Single launch. Per-n handshake instead of grid sync: the 64 blocks of a
// given n publish partials and count arrivals; the last arrival computes the
// softmax and release-stores flag[n]; the rest acquire-spin on that word.
// Deadlock-free by construction: 2048 blocks at __launch_bounds__(256,8)
// (VGPR capped at 64, LDS 2.3 KiB) = exactly 8 blocks/CU x 256 CU, so the
// whole grid is co-resident and every producer makes progress.

__global__ __launch_bounds__(256, 8) void fused_attn(
    const float* __restrict__ q, const float* __restrict__ k,
    float* __restrict__ partial, unsigned int* __restrict__ done,
    unsigned int* __restrict__ flag, float* __restrict__ probs_g,
    float* __restrict__ out) {
  const int t    = blockIdx.x;
  const int n    = blockIdx.y;
  const int tid  = threadIdx.x;
  const int lane = tid & 63;
  const int wave = tid >> 6;      // 0..3
  const int sub  = lane >> 4;     // quarter-wave within wave
  const int lq   = lane & 15;     // lane within quarter-wave -> l-group
  const int g    = wave * 4 + sub;

  __shared__ float sk[C];                 // k row: 1 KiB
  __shared__ float sred[4 * L];           // cross-wave reduce: 1 KiB
  __shared__ __align__(16) float probs[L];
  __shared__ unsigned int s_prev;

  // ---- Phase 1: partial[t][n][l] = sum_c q[n,t,c,l] * k[t,n,c] ----
  sk[tid] = k[(t * N + n) * C + tid];     // tid == c, coalesced
  __syncthreads();

  const float* __restrict__ qrow = q + ((size_t)(n * T + t) * C) * L + lq * 4;
  float4 acc = make_float4(0.f, 0.f, 0.f, 0.f);
  #pragma unroll 4
  for (int c = g; c < C; c += 16) {       // 16 iters, 1-KiB coalesced wave loads
    const float4 qv = *reinterpret_cast<const float4*>(qrow + (size_t)c * L);
    const float kv = sk[c];               // LDS broadcast within quarter-wave
    acc.x = fmaf(qv.x, kv, acc.x);
    acc.y = fmaf(qv.y, kv, acc.y);
    acc.z = fmaf(qv.z, kv, acc.z);
    acc.w = fmaf(qv.w, kv, acc.w);
  }
  acc.x += __shfl_xor(acc.x, 16); acc.y += __shfl_xor(acc.y, 16);
  acc.z += __shfl_xor(acc.z, 16); acc.w += __shfl_xor(acc.w, 16);
  acc.x += __shfl_xor(acc.x, 32); acc.y += __shfl_xor(acc.y, 32);
  acc.z += __shfl_xor(acc.z, 32); acc.w += __shfl_xor(acc.w, 32);

  if (lane < 16) {
    sred[wave * L + lq * 4 + 0] = acc.x;
    sred[wave * L + lq * 4 + 1] = acc.y;
    sred[wave * L + lq * 4 + 2] = acc.z;
    sred[wave * L + lq * 4 + 3] = acc.w;
  }
  __syncthreads();
  if (tid < L) {
    const float s = sred[tid] + sred[L + tid] + sred[2 * L + tid] + sred[3 * L + tid];
    partial[(size_t)t * (N * L) + n * L + tid] = s;
  }

  // ---- Publish partial row; count arrivals for this n (release pattern) ----
  __threadfence();                        // device-scope: partial visible
  __syncthreads();
  if (tid == 0) s_prev = atomicAdd(&done[n], 1u);   // device-scope by default
  __syncthreads();

  if (s_prev == T - 1) {
    // Last arrival for this n: reduce 64 partial rows, softmax, publish.
    __threadfence();                      // acquire: see remote partial rows
    float s = 0.f;
    #pragma unroll 4
    for (int b = wave * 16; b < wave * 16 + 16; ++b)
      s += __hip_atomic_load(&partial[(size_t)b * (N * L) + n * L + lane],
                             __ATOMIC_RELAXED, __HIP_MEMORY_SCOPE_AGENT);
    sred[wave * L + lane] = s;
    __syncthreads();
    if (tid < L) {
      float v = sred[tid] + sred[L + tid] + sred[2 * L + tid] + sred[3 * L + tid];
      float m = v;
      #pragma unroll
      for (int off = 32; off > 0; off >>= 1) m = fmaxf(m, __shfl_xor(m, off));
      const float e = __expf(v - m);
      float z = e;
      #pragma unroll
      for (int off = 32; off > 0; off >>= 1) z += __shfl_xor(z, off);
      __hip_atomic_store(&probs_g[n * L + tid], e / z,
                         __ATOMIC_RELAXED, __HIP_MEMORY_SCOPE_AGENT);
    }
    __threadfence();
    __syncthreads();
    if (tid == 0)
      __hip_atomic_store(&flag[n], 1u, __ATOMIC_RELEASE, __HIP_MEMORY_SCOPE_AGENT);
  }

  // ---- Wait for this n's probs; stage into LDS ----
  if (tid == 0) {
    while (__hip_atomic_load(&flag[n], __ATOMIC_ACQUIRE,
                             __HIP_MEMORY_SCOPE_AGENT) == 0u)
      __builtin_amdgcn_s_sleep(8);        // ~512-cycle poll interval
  }
  __syncthreads();
  if (tid < L)
    probs[tid] = __hip_atomic_load(&probs_g[n * L + tid],
                                   __ATOMIC_RELAXED, __HIP_MEMORY_SCOPE_AGENT);
  __syncthreads();

  // ---- Phase 2: out[t,n,c] = dot(q[n,t,c,:], probs[n,:]) ----
  // Thread tid == c. q row is L2/L3-resident (this block streamed it in
  // phase 1 on this XCD). Rolling unroll-4: no big register arrays (R4 lesson).
  const float* __restrict__ q2 = q + ((size_t)((n * T + t) * C + tid)) * L;
  float d = 0.f;
  #pragma unroll 4
  for (int i = 0; i < 16; ++i) {
    const float4 qv = *reinterpret_cast<const float4*>(q2 + i * 4);
    const float4 pv = *reinterpret_cast<const float4*>(&probs[i * 4]);
    d += qv.x * pv.x + qv.y * pv.y + qv.z * pv.z + qv.w * pv.w;
  }
  out[(size_t)(t * N + n) * C + tid] = d;  // coalesced 1 KiB per block
}

extern "C" void kernel_launch(void* const* d_in, const int* in_sizes, int n_in,
                              void* d_out, int out_size, void* d_ws, size_t ws_size,
                              hipStream_t stream) {
  const float* q = (const float*)d_in[0];   // query: (32,64,256,64) fp32
  const float* k = (const float*)d_in[1];   // key:   (64,32,256)    fp32
  float* out = (float*)d_out;               // out:   (64,32,256)    fp32

  float* partial = (float*)d_ws;                          // 512 KiB
  unsigned char* base = (unsigned char*)d_ws + (size_t)T * N * L * sizeof(float);
  unsigned int* done = (unsigned int*)base;               // N u32
  unsigned int* flag = done + N;                          // N u32
  float* probs_g = (float*)(base + 2 * N * sizeof(unsigned int));  // N*L floats

  // Zero the handshake words (poisoned workspace otherwise). Stream-ordered,
  // graph-capturable.
  hipMemsetAsync(base, 0, 2 * N * sizeof(unsigned int), stream);

  dim3 grid(T, N);                          // 2048 blocks x 256 threads
  fused_attn<<<grid, 256, 0, stream>>>(q, k, partial, done, flag, probs_g, out);
}

// Round 6
// 212.099 us; speedup vs baseline: 3.4084x; 3.4084x over previous
//
#include <hip/hip_runtime.h>

// Problem constants (fixed by reference setup_inputs).
#define N 32
#define T 64
#define C 256
#define L 64
#define TC (T * C)                     // 16384 (t,c) pairs per n
#define BLK_PER_N 64                   // blocks along the (t,c) axis per n
#define PAIRS_PER_BLK (TC / BLK_PER_N) // 256

// Kernel 1: partial[b][n][l] = sum over this block's (t,c) pairs of q[n,t,c,l]*k[t,n,c]
// Block = 256 threads = 4 waves = 16 quarter-waves of 16 lanes. A quarter-wave owns
// one (t,c) pair per iteration; lane lq loads float4 q[n,t,c,4lq..4lq+3] (coalesced
// 16B/lane) and FMAs against broadcast k[t,n,c]. 2048 blocks -> 32 waves/CU.
__global__ __launch_bounds__(256, 8) void scores_partial_kernel(
    const float* __restrict__ q, const float* __restrict__ k,
    float* __restrict__ partial) {
  const int n    = blockIdx.y;
  const int tid  = threadIdx.x;
  const int lane = tid & 63;
  const int wave = tid >> 6;      // 0..3
  const int sub  = lane >> 4;     // quarter-wave within wave, 0..3
  const int lq   = lane & 15;     // lane within quarter-wave -> l-group
  const int g    = wave * 4 + sub; // group id in block, 0..15

  const int p0 = blockIdx.x * PAIRS_PER_BLK;
  const float* qn = q + (size_t)n * TC * L;

  float4 acc = make_float4(0.f, 0.f, 0.f, 0.f);
  #pragma unroll 4
  for (int i = g; i < PAIRS_PER_BLK; i += 16) {   // 16 iterations
    const int p = p0 + i;
    const float4 qv = *reinterpret_cast<const float4*>(qn + (size_t)p * L + lq * 4);
    const int t = p >> 8;        // C == 256
    const int c = p & 255;
    const float kv = k[t * (N * C) + n * C + c];  // broadcast within quarter-wave
    acc.x = fmaf(qv.x, kv, acc.x);
    acc.y = fmaf(qv.y, kv, acc.y);
    acc.z = fmaf(qv.z, kv, acc.z);
    acc.w = fmaf(qv.w, kv, acc.w);
  }

  // Sum the 4 quarter-waves of this wave (same l-groups, different pairs).
  acc.x += __shfl_xor(acc.x, 16); acc.y += __shfl_xor(acc.y, 16);
  acc.z += __shfl_xor(acc.z, 16); acc.w += __shfl_xor(acc.w, 16);
  acc.x += __shfl_xor(acc.x, 32); acc.y += __shfl_xor(acc.y, 32);
  acc.z += __shfl_xor(acc.z, 32); acc.w += __shfl_xor(acc.w, 32);

  // Cross-wave reduction via LDS (1 KB).
  __shared__ float sdata[4 * L];
  if (lane < 16) {
    sdata[wave * L + lq * 4 + 0] = acc.x;
    sdata[wave * L + lq * 4 + 1] = acc.y;
    sdata[wave * L + lq * 4 + 2] = acc.z;
    sdata[wave * L + lq * 4 + 3] = acc.w;
  }
  __syncthreads();
  if (tid < L) {
    const float s = sdata[tid] + sdata[L + tid] + sdata[2 * L + tid] + sdata[3 * L + tid];
    partial[(size_t)blockIdx.x * (N * L) + n * L + tid] = s;  // deterministic, no atomics
  }
}

// Kernel 2: every block recomputes softmax(scores[n,:]) from the 64 partials
// (16 KiB, L2-hot; reduction split across all 4 waves), then computes
// out[t,n,c] = dot(q[n,t,c,:], probs[n,:]) with the same coalesced mapping.
__global__ __launch_bounds__(256, 8) void out_kernel(
    const float* __restrict__ q, const float* __restrict__ partial,
    float* __restrict__ out) {
  const int n    = blockIdx.y;
  const int tid  = threadIdx.x;
  const int lane = tid & 63;
  const int wave = tid >> 6;

  __shared__ float sred[4 * L];
  __shared__ float probs[L];
  {
    // Wave w sums partial blocks b in [16w, 16w+16); lane = l index.
    float s = 0.f;
    #pragma unroll 4
    for (int b = wave * 16; b < wave * 16 + 16; ++b)
      s += partial[(size_t)b * (N * L) + n * L + lane];
    sred[wave * L + lane] = s;
  }
  __syncthreads();
  if (tid < L) {  // wave 0 finishes softmax over l=tid
    float s = sred[tid] + sred[L + tid] + sred[2 * L + tid] + sred[3 * L + tid];
    float m = s;
    #pragma unroll
    for (int off = 32; off > 0; off >>= 1) m = fmaxf(m, __shfl_xor(m, off));
    const float e = __expf(s - m);
    float sum = e;
    #pragma unroll
    for (int off = 32; off > 0; off >>= 1) sum += __shfl_xor(sum, off);
    probs[tid] = e / sum;
  }
  __syncthreads();

  const int sub = lane >> 4;
  const int lq  = lane & 15;
  const int g   = wave * 4 + sub;

  const float4 pv = *reinterpret_cast<const float4*>(&probs[lq * 4]);
  const int p0 = blockIdx.x * PAIRS_PER_BLK;
  const float* qn = q + (size_t)n * TC * L;

  #pragma unroll 4
  for (int i = g; i < PAIRS_PER_BLK; i += 16) {   // 16 iterations
    const int p = p0 + i;
    const float4 qv = *reinterpret_cast<const float4*>(qn + (size_t)p * L + lq * 4);
    float d = qv.x * pv.x + qv.y * pv.y + qv.z * pv.z + qv.w * pv.w;
    // Reduce across the 16 lanes of the quarter-wave.
    d += __shfl_xor(d, 1);
    d += __shfl_xor(d, 2);
    d += __shfl_xor(d, 4);
    d += __shfl_xor(d, 8);
    if (lq == 0) {
      const int t = p >> 8;
      const int c = p & 255;
      out[t * (N * C) + n * C + c] = d;   // lanes 0/16/32/48 hit 4 consecutive floats
    }
  }
}

extern "C" void kernel_launch(void* const* d_in, const int* in_sizes, int n_in,
                              void* d_out, int out_size, void* d_ws, size_t ws_size,
                              hipStream_t stream) {
  const float* q = (const float*)d_in[0];   // query: (32,64,256,64) fp32
  const float* k = (const float*)d_in[1];   // key:   (64,32,256)    fp32
  float* out = (float*)d_out;               // out:   (64,32,256)    fp32
  float* partial = (float*)d_ws;            // [64][32][64] fp32 = 512 KiB scratch

  dim3 grid(BLK_PER_N, N);                  // 2048 blocks x 256 threads
  scores_partial_kernel<<<grid, 256, 0, stream>>>(q, k, partial);
  out_kernel<<<grid, 256, 0, stream>>>(q, partial, out);
}